// Round 13
// baseline (3745.226 us; speedup 1.0000x reference)
//
#include <hip/hip_runtime.h>
#include <stdint.h>

// P_TNCN: seq=512, batch=128, states=512, out=256, inv_tau=0.5,
// alpha=0.01, beta=0.5.  float32 I/O.
//
// Per step (per batch row b, independent across b):
//   h_prior = 0.5*h + 0.5*(tanh(h) @ w_r^T + b_r)          [w_i term == 0]
//   x_pred  = tanh(h_prior) @ w_o^T + b_o
//   error   = x_pred - x_t                                   (output)
//   h_post  = h_prior - 0.01*sign(h_prior) - 0.5*(error @ w_f^T)
//
// R15 = R14/R11 (2765us verified) + register weight staging.  R6 post-mortem
// (resolved): its 22GB FETCH explosion was VGPR SPILL to scratch caused by
// __launch_bounds__(512)'s ~128-VGPR cap vs 24 rotating uint4 buffers - the
// concept (weights resident in regs) is fine, the spill was the killer.
// This round: 12 NAMED uint4s (no rotation, no dynamic indexing) hold
// 6 A-rows (k16=7..12), 2 O-rows (thread's first two k16), 4 F-rows (o8=0..3)
// loaded ONCE before the t-loop -> 88 KB/step off the L2 stream (584->496KB)
// + warm data at each phase cold-start.  __launch_bounds__(512,1) lifts the
// VGPR cap (block needs 2 waves/SIMD, fine to 256 VGPR).  Accumulation order
// unchanged -> bitwise-identical output to R14.  Workspace: 640 KB + 8 B.

#define SEQ   512
#define BATCH 128
#define SD    512
#define OD    256
#define NST   7     // A rows staged in LDS (7*512*16B = 57344 B)

typedef _Float16 h2_t __attribute__((ext_vector_type(2)));

#if __has_builtin(__builtin_amdgcn_fdot2)
#define HAS_FDOT2 1
#else
#define HAS_FDOT2 0
#endif
#if __has_builtin(__builtin_amdgcn_sdot4)
#define HAS_SDOT4 1
#else
#define HAS_SDOT4 0
#endif

__device__ __forceinline__ float tanh_fast(float x) {
    float e = __expf(2.0f * x);
    return 1.0f - 2.0f / (e + 1.0f);
}

__device__ __forceinline__ uint32_t pack_h2(float a, float b) {
    h2_t v;
    v.x = (_Float16)a;
    v.y = (_Float16)b;
    return __builtin_bit_cast(uint32_t, v);
}

__device__ __forceinline__ float dot2acc(uint32_t w, uint32_t a, float acc) {
#if HAS_FDOT2
    return __builtin_amdgcn_fdot2(__builtin_bit_cast(h2_t, a),
                                  __builtin_bit_cast(h2_t, w), acc, false);
#else
    h2_t av = __builtin_bit_cast(h2_t, a);
    h2_t wv = __builtin_bit_cast(h2_t, w);
    acc += (float)av.x * (float)wv.x;
    acc += (float)av.y * (float)wv.y;
    return acc;
#endif
}

// f16 path (phase C): uint4 = 8 f16 weights vs 8 f16 acts.
__device__ __forceinline__ float dot8(uint4 w, uint4 a, float acc) {
    acc = dot2acc(w.x, a.x, acc);
    acc = dot2acc(w.y, a.y, acc);
    acc = dot2acc(w.z, a.z, acc);
    acc = dot2acc(w.w, a.w, acc);
    return acc;
}

// i8 path: 4 signed-i8 MACs per instruction, i32 accumulate.
__device__ __forceinline__ int dot4i(uint32_t w, uint32_t a, int acc) {
#if HAS_SDOT4
    return __builtin_amdgcn_sdot4((int)w, (int)a, acc, false);
#else
    #pragma unroll
    for (int i = 0; i < 4; ++i)
        acc += (int)(signed char)((w >> (8 * i)) & 0xffu)
             * (int)(signed char)((a >> (8 * i)) & 0xffu);
    return acc;
#endif
}
// uint4 = 16 i8 weights vs 16 i8 acts.
__device__ __forceinline__ int dot16i(uint4 w, uint4 a, int acc) {
    acc = dot4i(w.x, a.x, acc);
    acc = dot4i(w.y, a.y, acc);
    acc = dot4i(w.z, a.z, acc);
    acc = dot4i(w.w, a.w, acc);
    return acc;
}

// ---------------------------------------------------------------------------
// Workspace layout (uint4 units):
//   A8i [32][512] : i8 w_r, A8i[k16][s] bytes = w_r[s][16k16..16k16+15] (256 KB)
//   O8i [32][256] : i8 w_o, O8i[k16][o] likewise                        (128 KB)
//   F4  [32][512] : f16 w_f, F4[o8][s] = w_f[s][8o8..8o8+7]             (256 KB)
//   scales: 2 floats at uint4-offset 40960: max|w_r|, max|w_o|.
// ---------------------------------------------------------------------------

__global__ void compute_scales(const float* __restrict__ w_r,
                               const float* __restrict__ w_o,
                               float* __restrict__ sc)
{
    __shared__ float red[1024];
    const float* src = (blockIdx.x == 0) ? w_r : w_o;
    const int n = (blockIdx.x == 0) ? (512 * 512) : (256 * 512);
    float m = 0.0f;
    for (int i = threadIdx.x; i < n; i += 1024) m = fmaxf(m, fabsf(src[i]));
    red[threadIdx.x] = m;
    __syncthreads();
    for (int off = 512; off > 0; off >>= 1) {
        if (threadIdx.x < off)
            red[threadIdx.x] = fmaxf(red[threadIdx.x], red[threadIdx.x + off]);
        __syncthreads();
    }
    if (threadIdx.x == 0) sc[blockIdx.x] = fmaxf(red[0], 1e-20f);
}

__global__ void pack_weights(const float* __restrict__ w_o,
                             const float* __restrict__ w_r,
                             const float* __restrict__ w_f,
                             uint4* __restrict__ ws)
{
    const int nA = 32 * 512;   // 16384 uint4
    const int nO = 32 * 256;   //  8192
    const int nF = 32 * 512;   // 16384
    const float* sc = (const float*)(ws + nA + nO + nF);
    int i = blockIdx.x * 256 + threadIdx.x;
    if (i < nA + nO) {
        const float* p;
        float qs;
        if (i < nA) {
            int k16 = i >> 9, s = i & 511;
            p  = &w_r[s * 512 + 16 * k16];
            qs = 127.0f / sc[0];
        } else {
            int j = i - nA;
            int k16 = j >> 8, o = j & 255;
            p  = &w_o[o * 512 + 16 * k16];
            qs = 127.0f / sc[1];
        }
        uint32_t q[4];
        #pragma unroll
        for (int g = 0; g < 4; ++g) {
            uint32_t v = 0;
            #pragma unroll
            for (int j = 0; j < 4; ++j) {
                int qi = (int)rintf(p[4 * g + j] * qs);
                v |= ((uint32_t)qi & 0xffu) << (8 * j);
            }
            q[g] = v;
        }
        ws[i] = make_uint4(q[0], q[1], q[2], q[3]);
    } else if (i < nA + nO + nF) {
        int j = i - nA - nO;
        int o8 = j >> 9, s = j & 511;
        const float* p = &w_f[s * 256 + 8 * o8];
        ws[i] = make_uint4(pack_h2(p[0], p[1]), pack_h2(p[2], p[3]),
                           pack_h2(p[4], p[5]), pack_h2(p[6], p[7]));
    }
}

// ---------------------------------------------------------------------------
// Main sequential scan: one block per batch row, h state in registers (s=tid).
// A8i rows [0,NST) in LDS; A rows 7..12, O rows k160..k160+1, F rows 0..3 in
// named registers (loaded once).  Ascending-k accumulation (bitwise = R14).
// ---------------------------------------------------------------------------
__global__ __launch_bounds__(512, 1)
void tncn_scan(const float* __restrict__ x,       // [512][128][256]
               const float* __restrict__ h_init,  // [128][512]
               const float* __restrict__ b_o,     // [256]
               const float* __restrict__ b_r,     // [512]
               const uint4* __restrict__ wsv,
               float* __restrict__ out)           // [512][128][256]
{
    const uint4* A8i = wsv;                       // [32][512]
    const uint4* O8i = wsv + 32 * 512;            // [32][256]
    const uint4* F4  = wsv + 32 * 512 + 32 * 256; // [32][512]
    const float* scv = (const float*)(wsv + 32 * 512 + 32 * 256 + 32 * 512);

    extern __shared__ __align__(16) char smem_raw[];
    uint4* sA = (uint4*)smem_raw;                 // [NST*512] staged A8i rows

    __shared__ __align__(16) signed char thA8[512];  // i8 tanh(h_post)
    __shared__ __align__(16) signed char thB8[512];  // i8 tanh(h_prior)
    __shared__ __align__(16) _Float16 erh[256];      // f16 error vector
    __shared__ float part[512];                      // x_pred partial sums

    const int b   = blockIdx.x;
    const int tid = threadIdx.x;
    const int o   = tid & 255;
    const int kh  = tid >> 8;      // 0/1: k-half for phase B
    const int k160 = kh * 16;      // this thread's phase-B k16 base

    const float brf = b_r[tid];
    const float bof = (tid < 256) ? b_o[tid] : 0.0f;
    // Dequant factors: weight q*(max/127) times act q*(1/127).
    const float fA = scv[0] * (1.0f / 16129.0f);
    const float fO = scv[1] * (1.0f / 16129.0f);

    // Stage A8i rows [0, NST) into LDS once (coalesced).
    #pragma unroll
    for (int r = 0; r < NST; ++r)
        sA[r * 512 + tid] = A8i[r * 512 + tid];

    // Register-stage weight rows (named, loaded once; 12 uint4 = 48 VGPR).
    const uint4 rA0 = A8i[( 7 << 9) + tid];
    const uint4 rA1 = A8i[( 8 << 9) + tid];
    const uint4 rA2 = A8i[( 9 << 9) + tid];
    const uint4 rA3 = A8i[(10 << 9) + tid];
    const uint4 rA4 = A8i[(11 << 9) + tid];
    const uint4 rA5 = A8i[(12 << 9) + tid];
    const uint4 rO0 = O8i[( k160      << 8) + o];
    const uint4 rO1 = O8i[((k160 + 1) << 8) + o];
    const uint4 rF0 = F4[(0 << 9) + tid];
    const uint4 rF1 = F4[(1 << 9) + tid];
    const uint4 rF2 = F4[(2 << 9) + tid];
    const uint4 rF3 = F4[(3 << 9) + tid];

    float hpost = h_init[b * SD + tid];
    thA8[tid] = (signed char)__float2int_rn(tanh_fast(hpost) * 127.0f);
    __syncthreads();

    const uint4* actA = (const uint4*)thA8;   // [32] x 16 acts
    const uint4* actB = (const uint4*)thB8;

    for (int t = 0; t < SEQ; ++t) {
        // Hoisted x_t load (consumed one matvec later; latency hidden).
        float xv = 0.0f;
        if (tid < 256) xv = x[(t * BATCH + b) * OD + tid];

        // ---- Phase A: h_prior[s=tid] = 0.5*h + 0.5*(tanh(h)@w_r^T + b_r)
        int acci = 0;
        #pragma unroll
        for (int k16 = 0; k16 < NST; ++k16)            // LDS rows 0..6
            acci = dot16i(sA[(k16 << 9) + tid], actA[k16], acci);
        acci = dot16i(rA0, actA[ 7], acci);            // register rows 7..12
        acci = dot16i(rA1, actA[ 8], acci);
        acci = dot16i(rA2, actA[ 9], acci);
        acci = dot16i(rA3, actA[10], acci);
        acci = dot16i(rA4, actA[11], acci);
        acci = dot16i(rA5, actA[12], acci);
        #pragma unroll 5
        for (int k16 = 13; k16 < 32; ++k16)            // L2 stream 13..31
            acci = dot16i(A8i[(k16 << 9) + tid], actA[k16], acci);
        float hp = 0.5f * hpost + 0.5f * ((float)acci * fA + brf);
        thB8[tid] = (signed char)__float2int_rn(tanh_fast(hp) * 127.0f);
        __syncthreads();

        // ---- Phase B: x_pred[o] = tanh(h_prior)@w_o^T + b_o ; err = xp - x
        int accBi = 0;
        accBi = dot16i(rO0, actB[k160],     accBi);    // register rows
        accBi = dot16i(rO1, actB[k160 + 1], accBi);
        #pragma unroll 7
        for (int k16i = 2; k16i < 16; ++k16i) {        // L2 stream
            const int k16 = k160 + k16i;
            accBi = dot16i(O8i[(k16 << 8) + o], actB[k16], accBi);
        }
        part[tid] = (float)accBi * fO;
        __syncthreads();
        if (tid < 256) {
            float xp = part[tid] + part[tid + 256] + bof;
            float e  = xp - xv;
            erh[tid] = (_Float16)e;
            out[(t * BATCH + b) * OD + tid] = e;
        }
        __syncthreads();

        // ---- Phase C: h_post[s] = h_prior - 0.01*sign(h_prior) - 0.5*(er@w_f^T)
        float accC = 0.0f;
        accC = dot8(rF0, *(const uint4*)&erh[ 0], accC);   // register rows 0..3
        accC = dot8(rF1, *(const uint4*)&erh[ 8], accC);
        accC = dot8(rF2, *(const uint4*)&erh[16], accC);
        accC = dot8(rF3, *(const uint4*)&erh[24], accC);
        #pragma unroll 7
        for (int o8 = 4; o8 < 32; ++o8) {                  // L2 stream 4..31
            uint4 u = F4[(o8 << 9) + tid];
            uint4 e = *(const uint4*)&erh[8 * o8];
            accC = dot8(u, e, accC);
        }
        float sg = (hp > 0.0f) ? 1.0f : ((hp < 0.0f) ? -1.0f : 0.0f);
        hpost = hp - 0.01f * sg - 0.5f * accC;
        thA8[tid] = (signed char)__float2int_rn(tanh_fast(hpost) * 127.0f);
        __syncthreads();
    }
}

extern "C" void kernel_launch(void* const* d_in, const int* in_sizes, int n_in,
                              void* d_out, int out_size, void* d_ws, size_t ws_size,
                              hipStream_t stream)
{
    // setup_inputs order: x, h_init, w_o, b_o, w_r, b_r, w_f, w_i
    const float* x  = (const float*)d_in[0];
    const float* h0 = (const float*)d_in[1];
    const float* wo = (const float*)d_in[2];
    const float* bo = (const float*)d_in[3];
    const float* wr = (const float*)d_in[4];
    const float* br = (const float*)d_in[5];
    const float* wf = (const float*)d_in[6];
    // d_in[7] (w_i) multiplies a zeros tensor in the reference — unused.

    uint4* ws  = (uint4*)d_ws;
    float* out = (float*)d_out;

    const int total_img = 32 * 512 + 32 * 256 + 32 * 512;  // 40960 uint4
    float* sc = (float*)(ws + total_img);

    compute_scales<<<2, 1024, 0, stream>>>(wr, wo, sc);
    pack_weights<<<(total_img + 255) / 256, 256, 0, stream>>>(wo, wr, wf, ws);
    tncn_scan<<<BATCH, 512, NST * 512 * 16, stream>>>(x, h0, bo, br, ws, out);
}

// Round 14
// 2778.031 us; speedup vs baseline: 1.3482x; 1.3482x over previous
//
#include <hip/hip_runtime.h>
#include <stdint.h>

// P_TNCN: seq=512, batch=128, states=512, out=256, inv_tau=0.5,
// alpha=0.01, beta=0.5.  float32 I/O.
//
// Per step (per batch row b, independent across b):
//   h_prior = 0.5*h + 0.5*(tanh(h) @ w_r^T + b_r)          [w_i term == 0]
//   x_pred  = tanh(h_prior) @ w_o^T + b_o
//   error   = x_pred - x_t                                   (output)
//   h_post  = h_prior - 0.01*sign(h_prior) - 0.5*(error @ w_f^T)
//
// R16: PURE REVERT to R14/R11 (2765us, reproduced twice, +-0.4%).  R15's
// register staging regressed 35%: the compiler rematerialized the "staged"
// rows as per-iteration loads outside the unroll-batched clusters (VGPR 60,
// not 100+) -> added latency exposure.  Established pattern: R11's uniform
// sequential-unroll load structure is a sharp local optimum; five attack
// classes (occupancy/prefetch/byte-cut/barrier-cut/reg-staging) all
// regressed 15-35% by perturbing load batching.  No tweaks bundled here.
// R11 recap: w_r/w_o per-matrix-scaled i8 via v_dot4_i32_i8 (4 MACs/inst,
// zero decode); acts i8 at scale 127 (tanh range exact); w_f f16 via
// v_dot2_f32_f16 (sensitive O(1)-error path); 584 KB/step L2 weight stream
// at ~46 B/cy/CU (~72% of per-CU L2 port); NST=7 A-rows in 56 KB dyn LDS;
// 128 blk x 512 thr.  Workspace: 640 KB + 8 B.

#define SEQ   512
#define BATCH 128
#define SD    512
#define OD    256
#define NST   7     // A rows staged in LDS (7*512*16B = 57344 B)

typedef _Float16 h2_t __attribute__((ext_vector_type(2)));

#if __has_builtin(__builtin_amdgcn_fdot2)
#define HAS_FDOT2 1
#else
#define HAS_FDOT2 0
#endif
#if __has_builtin(__builtin_amdgcn_sdot4)
#define HAS_SDOT4 1
#else
#define HAS_SDOT4 0
#endif

__device__ __forceinline__ float tanh_fast(float x) {
    float e = __expf(2.0f * x);
    return 1.0f - 2.0f / (e + 1.0f);
}

__device__ __forceinline__ uint32_t pack_h2(float a, float b) {
    h2_t v;
    v.x = (_Float16)a;
    v.y = (_Float16)b;
    return __builtin_bit_cast(uint32_t, v);
}

__device__ __forceinline__ float dot2acc(uint32_t w, uint32_t a, float acc) {
#if HAS_FDOT2
    return __builtin_amdgcn_fdot2(__builtin_bit_cast(h2_t, a),
                                  __builtin_bit_cast(h2_t, w), acc, false);
#else
    h2_t av = __builtin_bit_cast(h2_t, a);
    h2_t wv = __builtin_bit_cast(h2_t, w);
    acc += (float)av.x * (float)wv.x;
    acc += (float)av.y * (float)wv.y;
    return acc;
#endif
}

// f16 path (phase C): uint4 = 8 f16 weights vs 8 f16 acts.
__device__ __forceinline__ float dot8(uint4 w, uint4 a, float acc) {
    acc = dot2acc(w.x, a.x, acc);
    acc = dot2acc(w.y, a.y, acc);
    acc = dot2acc(w.z, a.z, acc);
    acc = dot2acc(w.w, a.w, acc);
    return acc;
}

// i8 path: 4 signed-i8 MACs per instruction, i32 accumulate.
__device__ __forceinline__ int dot4i(uint32_t w, uint32_t a, int acc) {
#if HAS_SDOT4
    return __builtin_amdgcn_sdot4((int)w, (int)a, acc, false);
#else
    #pragma unroll
    for (int i = 0; i < 4; ++i)
        acc += (int)(signed char)((w >> (8 * i)) & 0xffu)
             * (int)(signed char)((a >> (8 * i)) & 0xffu);
    return acc;
#endif
}
// uint4 = 16 i8 weights vs 16 i8 acts.
__device__ __forceinline__ int dot16i(uint4 w, uint4 a, int acc) {
    acc = dot4i(w.x, a.x, acc);
    acc = dot4i(w.y, a.y, acc);
    acc = dot4i(w.z, a.z, acc);
    acc = dot4i(w.w, a.w, acc);
    return acc;
}

// ---------------------------------------------------------------------------
// Workspace layout (uint4 units):
//   A8i [32][512] : i8 w_r, A8i[k16][s] bytes = w_r[s][16k16..16k16+15] (256 KB)
//   O8i [32][256] : i8 w_o, O8i[k16][o] likewise                        (128 KB)
//   F4  [32][512] : f16 w_f, F4[o8][s] = w_f[s][8o8..8o8+7]             (256 KB)
//   scales: 2 floats at uint4-offset 40960: max|w_r|, max|w_o|.
// ---------------------------------------------------------------------------

__global__ void compute_scales(const float* __restrict__ w_r,
                               const float* __restrict__ w_o,
                               float* __restrict__ sc)
{
    __shared__ float red[1024];
    const float* src = (blockIdx.x == 0) ? w_r : w_o;
    const int n = (blockIdx.x == 0) ? (512 * 512) : (256 * 512);
    float m = 0.0f;
    for (int i = threadIdx.x; i < n; i += 1024) m = fmaxf(m, fabsf(src[i]));
    red[threadIdx.x] = m;
    __syncthreads();
    for (int off = 512; off > 0; off >>= 1) {
        if (threadIdx.x < off)
            red[threadIdx.x] = fmaxf(red[threadIdx.x], red[threadIdx.x + off]);
        __syncthreads();
    }
    if (threadIdx.x == 0) sc[blockIdx.x] = fmaxf(red[0], 1e-20f);
}

__global__ void pack_weights(const float* __restrict__ w_o,
                             const float* __restrict__ w_r,
                             const float* __restrict__ w_f,
                             uint4* __restrict__ ws)
{
    const int nA = 32 * 512;   // 16384 uint4
    const int nO = 32 * 256;   //  8192
    const int nF = 32 * 512;   // 16384
    const float* sc = (const float*)(ws + nA + nO + nF);
    int i = blockIdx.x * 256 + threadIdx.x;
    if (i < nA + nO) {
        const float* p;
        float qs;
        if (i < nA) {
            int k16 = i >> 9, s = i & 511;
            p  = &w_r[s * 512 + 16 * k16];
            qs = 127.0f / sc[0];
        } else {
            int j = i - nA;
            int k16 = j >> 8, o = j & 255;
            p  = &w_o[o * 512 + 16 * k16];
            qs = 127.0f / sc[1];
        }
        uint32_t q[4];
        #pragma unroll
        for (int g = 0; g < 4; ++g) {
            uint32_t v = 0;
            #pragma unroll
            for (int j = 0; j < 4; ++j) {
                int qi = (int)rintf(p[4 * g + j] * qs);
                v |= ((uint32_t)qi & 0xffu) << (8 * j);
            }
            q[g] = v;
        }
        ws[i] = make_uint4(q[0], q[1], q[2], q[3]);
    } else if (i < nA + nO + nF) {
        int j = i - nA - nO;
        int o8 = j >> 9, s = j & 511;
        const float* p = &w_f[s * 256 + 8 * o8];
        ws[i] = make_uint4(pack_h2(p[0], p[1]), pack_h2(p[2], p[3]),
                           pack_h2(p[4], p[5]), pack_h2(p[6], p[7]));
    }
}

// ---------------------------------------------------------------------------
// Main sequential scan: one block per batch row, h state in registers (s=tid).
// A8i rows [0,NST) live in LDS (loaded once); ascending-k accumulation.
// ---------------------------------------------------------------------------
__global__ __launch_bounds__(512)
void tncn_scan(const float* __restrict__ x,       // [512][128][256]
               const float* __restrict__ h_init,  // [128][512]
               const float* __restrict__ b_o,     // [256]
               const float* __restrict__ b_r,     // [512]
               const uint4* __restrict__ wsv,
               float* __restrict__ out)           // [512][128][256]
{
    const uint4* A8i = wsv;                       // [32][512]
    const uint4* O8i = wsv + 32 * 512;            // [32][256]
    const uint4* F4  = wsv + 32 * 512 + 32 * 256; // [32][512]
    const float* scv = (const float*)(wsv + 32 * 512 + 32 * 256 + 32 * 512);

    extern __shared__ __align__(16) char smem_raw[];
    uint4* sA = (uint4*)smem_raw;                 // [NST*512] staged A8i rows

    __shared__ __align__(16) signed char thA8[512];  // i8 tanh(h_post)
    __shared__ __align__(16) signed char thB8[512];  // i8 tanh(h_prior)
    __shared__ __align__(16) _Float16 erh[256];      // f16 error vector
    __shared__ float part[512];                      // x_pred partial sums

    const int b   = blockIdx.x;
    const int tid = threadIdx.x;
    const int o   = tid & 255;
    const int kh  = tid >> 8;    // 0/1: k-half for phase B

    const float brf = b_r[tid];
    const float bof = (tid < 256) ? b_o[tid] : 0.0f;
    // Dequant factors: weight q*(max/127) times act q*(1/127).
    const float fA = scv[0] * (1.0f / 16129.0f);
    const float fO = scv[1] * (1.0f / 16129.0f);

    // Stage A8i rows [0, NST) into LDS once (coalesced).
    #pragma unroll
    for (int r = 0; r < NST; ++r)
        sA[r * 512 + tid] = A8i[r * 512 + tid];

    float hpost = h_init[b * SD + tid];
    thA8[tid] = (signed char)__float2int_rn(tanh_fast(hpost) * 127.0f);
    __syncthreads();

    const uint4* actA = (const uint4*)thA8;   // [32] x 16 acts
    const uint4* actB = (const uint4*)thB8;

    for (int t = 0; t < SEQ; ++t) {
        // Hoisted x_t load (consumed one matvec later; latency hidden).
        float xv = 0.0f;
        if (tid < 256) xv = x[(t * BATCH + b) * OD + tid];

        // ---- Phase A: h_prior[s=tid] = 0.5*h + 0.5*(tanh(h)@w_r^T + b_r)
        int acci = 0;
        #pragma unroll
        for (int k16 = 0; k16 < NST; ++k16)            // LDS-staged rows
            acci = dot16i(sA[(k16 << 9) + tid], actA[k16], acci);
        #pragma unroll 5
        for (int k16 = NST; k16 < 32; ++k16)           // L2 stream
            acci = dot16i(A8i[(k16 << 9) + tid], actA[k16], acci);
        float hp = 0.5f * hpost + 0.5f * ((float)acci * fA + brf);
        thB8[tid] = (signed char)__float2int_rn(tanh_fast(hp) * 127.0f);
        __syncthreads();

        // ---- Phase B: x_pred[o] = tanh(h_prior)@w_o^T + b_o ; err = xp - x
        int accBi = 0;
        {
            const int k160 = kh * 16;
            #pragma unroll 8
            for (int k16i = 0; k16i < 16; ++k16i) {
                const int k16 = k160 + k16i;
                accBi = dot16i(O8i[(k16 << 8) + o], actB[k16], accBi);
            }
        }
        part[tid] = (float)accBi * fO;
        __syncthreads();
        if (tid < 256) {
            float xp = part[tid] + part[tid + 256] + bof;
            float e  = xp - xv;
            erh[tid] = (_Float16)e;
            out[(t * BATCH + b) * OD + tid] = e;
        }
        __syncthreads();

        // ---- Phase C: h_post[s] = h_prior - 0.01*sign(h_prior) - 0.5*(er@w_f^T)
        float accC = 0.0f;
        #pragma unroll 8
        for (int o8 = 0; o8 < 32; ++o8) {
            uint4 u = F4[(o8 << 9) + tid];
            uint4 e = *(const uint4*)&erh[8 * o8];
            accC = dot8(u, e, accC);
        }
        float sg = (hp > 0.0f) ? 1.0f : ((hp < 0.0f) ? -1.0f : 0.0f);
        hpost = hp - 0.01f * sg - 0.5f * accC;
        thA8[tid] = (signed char)__float2int_rn(tanh_fast(hpost) * 127.0f);
        __syncthreads();
    }
}

extern "C" void kernel_launch(void* const* d_in, const int* in_sizes, int n_in,
                              void* d_out, int out_size, void* d_ws, size_t ws_size,
                              hipStream_t stream)
{
    // setup_inputs order: x, h_init, w_o, b_o, w_r, b_r, w_f, w_i
    const float* x  = (const float*)d_in[0];
    const float* h0 = (const float*)d_in[1];
    const float* wo = (const float*)d_in[2];
    const float* bo = (const float*)d_in[3];
    const float* wr = (const float*)d_in[4];
    const float* br = (const float*)d_in[5];
    const float* wf = (const float*)d_in[6];
    // d_in[7] (w_i) multiplies a zeros tensor in the reference — unused.

    uint4* ws  = (uint4*)d_ws;
    float* out = (float*)d_out;

    const int total_img = 32 * 512 + 32 * 256 + 32 * 512;  // 40960 uint4
    float* sc = (float*)(ws + total_img);

    compute_scales<<<2, 1024, 0, stream>>>(wr, wo, sc);
    pack_weights<<<(total_img + 255) / 256, 256, 0, stream>>>(wo, wr, wf, ws);
    tncn_scan<<<BATCH, 512, NST * 512 * 16, stream>>>(x, h0, bo, br, ws, out);
}

// Round 15
// 2670.600 us; speedup vs baseline: 1.4024x; 1.0402x over previous
//
#include <hip/hip_runtime.h>
#include <stdint.h>

// P_TNCN: seq=512, batch=128, states=512, out=256, inv_tau=0.5,
// alpha=0.01, beta=0.5.  float32 I/O.
//
// Per step (per batch row b, independent across b):
//   h_prior = 0.5*h + 0.5*(tanh(h) @ w_r^T + b_r)          [w_i term == 0]
//   x_pred  = tanh(h_prior) @ w_o^T + b_o
//   error   = x_pred - x_t                                   (output)
//   h_post  = h_prior - 0.01*sign(h_prior) - 0.5*(error @ w_f^T)
//
// R17 = R16/R11 (2765-2778us, reproduced 3x) + ONE worst-case-neutral probe:
// extend A-row LDS staging from NST=7 (56 KB, default limit) to NST=18
// (144 KB dynamic) via hipFuncSetAttribute, VERIFIED with
// hipFuncGetAttributes before use; fallback launches the NST=7 instantiation
// which is byte-identical to R16.  Mechanism: R9 proved LDS staging is the
// one stream-shrink that works inside this structure; this moves 88 KB/step
// more off the per-CU L2 port (584 -> 496 KB/step).  Same ascending-k
// accumulation order in both variants -> absmax bit-identical.  1 block/CU,
// 147.5 KB LDS < 160 KB pool, no occupancy change.  Workspace: 640 KB + 8 B.

#define SEQ   512
#define BATCH 128
#define SD    512
#define OD    256

typedef _Float16 h2_t __attribute__((ext_vector_type(2)));

#if __has_builtin(__builtin_amdgcn_fdot2)
#define HAS_FDOT2 1
#else
#define HAS_FDOT2 0
#endif
#if __has_builtin(__builtin_amdgcn_sdot4)
#define HAS_SDOT4 1
#else
#define HAS_SDOT4 0
#endif

__device__ __forceinline__ float tanh_fast(float x) {
    float e = __expf(2.0f * x);
    return 1.0f - 2.0f / (e + 1.0f);
}

__device__ __forceinline__ uint32_t pack_h2(float a, float b) {
    h2_t v;
    v.x = (_Float16)a;
    v.y = (_Float16)b;
    return __builtin_bit_cast(uint32_t, v);
}

__device__ __forceinline__ float dot2acc(uint32_t w, uint32_t a, float acc) {
#if HAS_FDOT2
    return __builtin_amdgcn_fdot2(__builtin_bit_cast(h2_t, a),
                                  __builtin_bit_cast(h2_t, w), acc, false);
#else
    h2_t av = __builtin_bit_cast(h2_t, a);
    h2_t wv = __builtin_bit_cast(h2_t, w);
    acc += (float)av.x * (float)wv.x;
    acc += (float)av.y * (float)wv.y;
    return acc;
#endif
}

// f16 path (phase C): uint4 = 8 f16 weights vs 8 f16 acts.
__device__ __forceinline__ float dot8(uint4 w, uint4 a, float acc) {
    acc = dot2acc(w.x, a.x, acc);
    acc = dot2acc(w.y, a.y, acc);
    acc = dot2acc(w.z, a.z, acc);
    acc = dot2acc(w.w, a.w, acc);
    return acc;
}

// i8 path: 4 signed-i8 MACs per instruction, i32 accumulate.
__device__ __forceinline__ int dot4i(uint32_t w, uint32_t a, int acc) {
#if HAS_SDOT4
    return __builtin_amdgcn_sdot4((int)w, (int)a, acc, false);
#else
    #pragma unroll
    for (int i = 0; i < 4; ++i)
        acc += (int)(signed char)((w >> (8 * i)) & 0xffu)
             * (int)(signed char)((a >> (8 * i)) & 0xffu);
    return acc;
#endif
}
// uint4 = 16 i8 weights vs 16 i8 acts.
__device__ __forceinline__ int dot16i(uint4 w, uint4 a, int acc) {
    acc = dot4i(w.x, a.x, acc);
    acc = dot4i(w.y, a.y, acc);
    acc = dot4i(w.z, a.z, acc);
    acc = dot4i(w.w, a.w, acc);
    return acc;
}

// ---------------------------------------------------------------------------
// Workspace layout (uint4 units):
//   A8i [32][512] : i8 w_r, A8i[k16][s] bytes = w_r[s][16k16..16k16+15] (256 KB)
//   O8i [32][256] : i8 w_o, O8i[k16][o] likewise                        (128 KB)
//   F4  [32][512] : f16 w_f, F4[o8][s] = w_f[s][8o8..8o8+7]             (256 KB)
//   scales: 2 floats at uint4-offset 40960: max|w_r|, max|w_o|.
// ---------------------------------------------------------------------------

__global__ void compute_scales(const float* __restrict__ w_r,
                               const float* __restrict__ w_o,
                               float* __restrict__ sc)
{
    __shared__ float red[1024];
    const float* src = (blockIdx.x == 0) ? w_r : w_o;
    const int n = (blockIdx.x == 0) ? (512 * 512) : (256 * 512);
    float m = 0.0f;
    for (int i = threadIdx.x; i < n; i += 1024) m = fmaxf(m, fabsf(src[i]));
    red[threadIdx.x] = m;
    __syncthreads();
    for (int off = 512; off > 0; off >>= 1) {
        if (threadIdx.x < off)
            red[threadIdx.x] = fmaxf(red[threadIdx.x], red[threadIdx.x + off]);
        __syncthreads();
    }
    if (threadIdx.x == 0) sc[blockIdx.x] = fmaxf(red[0], 1e-20f);
}

__global__ void pack_weights(const float* __restrict__ w_o,
                             const float* __restrict__ w_r,
                             const float* __restrict__ w_f,
                             uint4* __restrict__ ws)
{
    const int nA = 32 * 512;   // 16384 uint4
    const int nO = 32 * 256;   //  8192
    const int nF = 32 * 512;   // 16384
    const float* sc = (const float*)(ws + nA + nO + nF);
    int i = blockIdx.x * 256 + threadIdx.x;
    if (i < nA + nO) {
        const float* p;
        float qs;
        if (i < nA) {
            int k16 = i >> 9, s = i & 511;
            p  = &w_r[s * 512 + 16 * k16];
            qs = 127.0f / sc[0];
        } else {
            int j = i - nA;
            int k16 = j >> 8, o = j & 255;
            p  = &w_o[o * 512 + 16 * k16];
            qs = 127.0f / sc[1];
        }
        uint32_t q[4];
        #pragma unroll
        for (int g = 0; g < 4; ++g) {
            uint32_t v = 0;
            #pragma unroll
            for (int j = 0; j < 4; ++j) {
                int qi = (int)rintf(p[4 * g + j] * qs);
                v |= ((uint32_t)qi & 0xffu) << (8 * j);
            }
            q[g] = v;
        }
        ws[i] = make_uint4(q[0], q[1], q[2], q[3]);
    } else if (i < nA + nO + nF) {
        int j = i - nA - nO;
        int o8 = j >> 9, s = j & 511;
        const float* p = &w_f[s * 256 + 8 * o8];
        ws[i] = make_uint4(pack_h2(p[0], p[1]), pack_h2(p[2], p[3]),
                           pack_h2(p[4], p[5]), pack_h2(p[6], p[7]));
    }
}

// ---------------------------------------------------------------------------
// Main sequential scan: one block per batch row, h state in registers (s=tid).
// A8i rows [0,NSTAGE) live in LDS (loaded once); ascending-k accumulation.
// NSTAGE=7 instantiation is byte-identical to R16's kernel.
// ---------------------------------------------------------------------------
template <int NSTAGE>
__global__ __launch_bounds__(512)
void tncn_scan(const float* __restrict__ x,       // [512][128][256]
               const float* __restrict__ h_init,  // [128][512]
               const float* __restrict__ b_o,     // [256]
               const float* __restrict__ b_r,     // [512]
               const uint4* __restrict__ wsv,
               float* __restrict__ out)           // [512][128][256]
{
    const uint4* A8i = wsv;                       // [32][512]
    const uint4* O8i = wsv + 32 * 512;            // [32][256]
    const uint4* F4  = wsv + 32 * 512 + 32 * 256; // [32][512]
    const float* scv = (const float*)(wsv + 32 * 512 + 32 * 256 + 32 * 512);

    extern __shared__ __align__(16) char smem_raw[];
    uint4* sA = (uint4*)smem_raw;                 // [NSTAGE*512] staged A8i

    __shared__ __align__(16) signed char thA8[512];  // i8 tanh(h_post)
    __shared__ __align__(16) signed char thB8[512];  // i8 tanh(h_prior)
    __shared__ __align__(16) _Float16 erh[256];      // f16 error vector
    __shared__ float part[512];                      // x_pred partial sums

    const int b   = blockIdx.x;
    const int tid = threadIdx.x;
    const int o   = tid & 255;
    const int kh  = tid >> 8;    // 0/1: k-half for phase B

    const float brf = b_r[tid];
    const float bof = (tid < 256) ? b_o[tid] : 0.0f;
    // Dequant factors: weight q*(max/127) times act q*(1/127).
    const float fA = scv[0] * (1.0f / 16129.0f);
    const float fO = scv[1] * (1.0f / 16129.0f);

    // Stage A8i rows [0, NSTAGE) into LDS once (coalesced).
    #pragma unroll
    for (int r = 0; r < NSTAGE; ++r)
        sA[r * 512 + tid] = A8i[r * 512 + tid];

    float hpost = h_init[b * SD + tid];
    thA8[tid] = (signed char)__float2int_rn(tanh_fast(hpost) * 127.0f);
    __syncthreads();

    const uint4* actA = (const uint4*)thA8;   // [32] x 16 acts
    const uint4* actB = (const uint4*)thB8;

    for (int t = 0; t < SEQ; ++t) {
        // Hoisted x_t load (consumed one matvec later; latency hidden).
        float xv = 0.0f;
        if (tid < 256) xv = x[(t * BATCH + b) * OD + tid];

        // ---- Phase A: h_prior[s=tid] = 0.5*h + 0.5*(tanh(h)@w_r^T + b_r)
        int acci = 0;
        #pragma unroll
        for (int k16 = 0; k16 < NSTAGE; ++k16)         // LDS-staged rows
            acci = dot16i(sA[(k16 << 9) + tid], actA[k16], acci);
        #pragma unroll 5
        for (int k16 = NSTAGE; k16 < 32; ++k16)        // L2 stream
            acci = dot16i(A8i[(k16 << 9) + tid], actA[k16], acci);
        float hp = 0.5f * hpost + 0.5f * ((float)acci * fA + brf);
        thB8[tid] = (signed char)__float2int_rn(tanh_fast(hp) * 127.0f);
        __syncthreads();

        // ---- Phase B: x_pred[o] = tanh(h_prior)@w_o^T + b_o ; err = xp - x
        int accBi = 0;
        {
            const int k160 = kh * 16;
            #pragma unroll 8
            for (int k16i = 0; k16i < 16; ++k16i) {
                const int k16 = k160 + k16i;
                accBi = dot16i(O8i[(k16 << 8) + o], actB[k16], accBi);
            }
        }
        part[tid] = (float)accBi * fO;
        __syncthreads();
        if (tid < 256) {
            float xp = part[tid] + part[tid + 256] + bof;
            float e  = xp - xv;
            erh[tid] = (_Float16)e;
            out[(t * BATCH + b) * OD + tid] = e;
        }
        __syncthreads();

        // ---- Phase C: h_post[s] = h_prior - 0.01*sign(h_prior) - 0.5*(er@w_f^T)
        float accC = 0.0f;
        #pragma unroll 8
        for (int o8 = 0; o8 < 32; ++o8) {
            uint4 u = F4[(o8 << 9) + tid];
            uint4 e = *(const uint4*)&erh[8 * o8];
            accC = dot8(u, e, accC);
        }
        float sg = (hp > 0.0f) ? 1.0f : ((hp < 0.0f) ? -1.0f : 0.0f);
        hpost = hp - 0.01f * sg - 0.5f * accC;
        thA8[tid] = (signed char)__float2int_rn(tanh_fast(hpost) * 127.0f);
        __syncthreads();
    }
}

extern "C" void kernel_launch(void* const* d_in, const int* in_sizes, int n_in,
                              void* d_out, int out_size, void* d_ws, size_t ws_size,
                              hipStream_t stream)
{
    // setup_inputs order: x, h_init, w_o, b_o, w_r, b_r, w_f, w_i
    const float* x  = (const float*)d_in[0];
    const float* h0 = (const float*)d_in[1];
    const float* wo = (const float*)d_in[2];
    const float* bo = (const float*)d_in[3];
    const float* wr = (const float*)d_in[4];
    const float* br = (const float*)d_in[5];
    const float* wf = (const float*)d_in[6];
    // d_in[7] (w_i) multiplies a zeros tensor in the reference — unused.

    uint4* ws  = (uint4*)d_ws;
    float* out = (float*)d_out;

    const int total_img = 32 * 512 + 32 * 256 + 32 * 512;  // 40960 uint4
    float* sc = (float*)(ws + total_img);

    compute_scales<<<2, 1024, 0, stream>>>(wr, wo, sc);
    pack_weights<<<(total_img + 255) / 256, 256, 0, stream>>>(wo, wr, wf, ws);

    // Probe: opt the NST=18 variant into 144 KB dynamic LDS and VERIFY the
    // attribute took effect.  Any failure -> NST=7 launch (== R16 exactly).
    constexpr int kBig   = 18;
    constexpr int kBigSz = kBig * 512 * 16;       // 147456 B
    static int nsel = -1;
    if (nsel < 0) {
        nsel = 7;
        hipError_t e = hipFuncSetAttribute(
            (const void*)tncn_scan<kBig>,
            hipFuncAttributeMaxDynamicSharedMemorySize, kBigSz);
        if (e == hipSuccess) {
            hipFuncAttributes fa;
            if (hipFuncGetAttributes(&fa, (const void*)tncn_scan<kBig>) ==
                    hipSuccess &&
                fa.maxDynamicSharedSizeBytes >= kBigSz) {
                nsel = kBig;
            }
        }
    }
    if (nsel == kBig) {
        tncn_scan<kBig><<<BATCH, 512, kBigSz, stream>>>(x, h0, bo, br, ws, out);
    } else {
        tncn_scan<7><<<BATCH, 512, 7 * 512 * 16, stream>>>(x, h0, bo, br, ws, out);
    }
}